// Round 1
// baseline (64569.684 us; speedup 1.0000x reference)
//
#include <hip/hip_runtime.h>
#include <stdint.h>

#define T_LEN 8192

__device__ __forceinline__ float sigf(float x) {
    return 1.0f / (1.0f + __expf(-x));
}
__device__ __forceinline__ float tanh_fast(float x) {
    float e = __expf(2.0f * x);
    return 1.0f - 2.0f / (e + 1.0f);   // -> -1 / +1 correctly at +-inf
}

// One LSTM layer scan.
//  H: hidden size. NWG: workgroups cooperating on the layer. TPB: threads/block.
//  SUBS: threads per gate-row (each thread holds CH=H/SUBS weights in VGPRs).
//  XGMODE: 0 = xg[t][4H] from global, 1 = fused from scalar x[t] (e1), 2 = constant xg row (d1).
//  LID: unique layer id for sync-tag epochs (multi-WG layers only).
// Sync between WGs: each h element is published as a u64 (tag<<32 | f32 bits) via
// relaxed agent-scope atomics; consumers poll the tag. No fences/flags needed since
// value+tag are one atomic word.
template<int H, int NWG, int TPB, int SUBS, int XGMODE, int LID, bool WRITE_YS, bool WRITE_Z>
__global__ __launch_bounds__(TPB)
void lstm_scan(const float* __restrict__ Whh,          // [4H][H]
               const float* __restrict__ xg,           // per XGMODE
               const float* __restrict__ wih0,         // XGMODE==1: Wih[4H][1]
               const float* __restrict__ bih,          // XGMODE==1 only
               const float* __restrict__ bhh,          // XGMODE==1 only
               float* __restrict__ ys,                 // [T][H] plain (if WRITE_YS)
               unsigned long long* __restrict__ hst,   // [T][H] tagged (if NWG>1)
               float* __restrict__ zout)               // [H] final h (if WRITE_Z)
{
    constexpr int ROWS = 4 * H / NWG;   // gate-rows owned by this WG
    constexpr int HJ   = H / NWG;       // h-elements owned by this WG
    constexpr int CH   = H / SUBS;      // weights per thread
    constexpr int CHP  = CH + 8;        // padded chunk stride (bank spread + 16B align)
    static_assert(ROWS * SUBS == TPB, "bad layout");

    const int tid = threadIdx.x;
    const int wg  = (NWG > 1) ? blockIdx.x : 0;
    const int q   = tid / SUBS;         // local gate-row
    const int sub = tid % SUBS;         // column chunk
    const int g   = q / HJ;             // gate 0..3 (i,f,g,o)
    const int jj  = q % HJ;
    const int grow = g * H + wg * HJ + jj;   // global gate-row

    __shared__ float hbuf[SUBS * CHP];
    __shared__ float act[ROWS];
    __shared__ int abortf;

    // recurrent weights -> VGPRs (statically indexed)
    float4 wreg[CH / 4];
    {
        const float4* wr = (const float4*)(Whh + (size_t)grow * H + sub * CH);
        #pragma unroll
        for (int i = 0; i < CH / 4; ++i) wreg[i] = wr[i];
    }

    float w0 = 0.f, bs = 0.f, xg_const = 0.f;
    if constexpr (XGMODE == 1) { w0 = wih0[grow]; bs = bih[grow] + bhh[grow]; }
    if constexpr (XGMODE == 2) { xg_const = xg[grow]; }

    float c = 0.f;                       // cell state, valid in tid < HJ
    for (int k = tid; k < SUBS * CHP; k += TPB) hbuf[k] = 0.f;
    if (tid == 0) abortf = 0;
    __syncthreads();

    for (int t = 0; t < T_LEN; ++t) {
        // ---- phase 1: xg prefetch (independent of h) + obtain h[t-1] ----
        float xgv = 0.f;
        if (sub == 0) {
            if constexpr (XGMODE == 0)      xgv = xg[(size_t)t * (4 * H) + grow];
            else if constexpr (XGMODE == 1) xgv = fmaf(xg[t], w0, bs);
            else                            xgv = xg_const;
        }
        if constexpr (NWG > 1) {
            if (t > 0 && tid < H) {
                const size_t idx = (size_t)(t - 1) * H + tid;
                const unsigned want = (unsigned)(LID * T_LEN + t);
                unsigned long long v;
                int spin = 0;
                for (;;) {
                    v = __hip_atomic_load(&hst[idx], __ATOMIC_RELAXED,
                                          __HIP_MEMORY_SCOPE_AGENT);
                    if ((unsigned)(v >> 32) == want) break;
                    if (++spin >= (1 << 20)) { abortf = 1; break; }  // no-hang guard
                }
                union { unsigned u; float f; } cv;
                cv.u = (unsigned)v;
                hbuf[(tid / CH) * CHP + (tid % CH)] = cv.f;
            }
        }
        __syncthreads();
        if (abortf) break;

        // ---- phase 2: partial dot over this thread's chunk ----
        float4 a4 = make_float4(0.f, 0.f, 0.f, 0.f);
        const float4* hv4 = (const float4*)&hbuf[sub * CHP];
        #pragma unroll
        for (int i = 0; i < CH / 4; ++i) {
            float4 hv = hv4[i];
            float4 wv = wreg[i];
            a4.x = fmaf(wv.x, hv.x, a4.x);
            a4.y = fmaf(wv.y, hv.y, a4.y);
            a4.z = fmaf(wv.z, hv.z, a4.z);
            a4.w = fmaf(wv.w, hv.w, a4.w);
        }
        float acc = (a4.x + a4.y) + (a4.z + a4.w);
        #pragma unroll
        for (int d = 1; d < SUBS; d <<= 1) acc += __shfl_xor(acc, d);

        if (sub == 0) {
            float gv = acc + xgv;
            act[q] = (g == 2) ? tanh_fast(gv) : sigf(gv);
        }
        __syncthreads();

        // ---- phase 3: state update on owned j's, publish h ----
        if (tid < HJ) {
            float iv = act[tid];
            float fv = act[HJ + tid];
            float gc = act[2 * HJ + tid];
            float ov = act[3 * HJ + tid];
            c = fmaf(fv, c, iv * gc);
            float h = ov * tanh_fast(c);
            if constexpr (WRITE_YS) ys[(size_t)t * H + wg * HJ + tid] = h;
            if constexpr (NWG > 1) {
                union { float f; unsigned u; } cv;
                cv.f = h;
                unsigned long long pk =
                    ((unsigned long long)(unsigned)(LID * T_LEN + t + 1) << 32) | cv.u;
                __hip_atomic_store(&hst[(size_t)t * H + wg * HJ + tid], pk,
                                   __ATOMIC_RELAXED, __HIP_MEMORY_SCOPE_AGENT);
            } else {
                hbuf[(tid / CH) * CHP + (tid % CH)] = h;   // single-WG: LDS only
            }
            if constexpr (WRITE_Z) { if (t == T_LEN - 1) zout[tid] = h; }
        }
        __syncthreads();
    }
}

// C[M][N] = A[M][K] @ B[N][K]^T + (bih+bhh)[N]   (xg precompute)
__global__ __launch_bounds__(256)
void gemm_bias(const float* __restrict__ A, const float* __restrict__ B,
               const float* __restrict__ bih, const float* __restrict__ bhh,
               float* __restrict__ C, int M, int N, int K)
{
    __shared__ float As[16][72];
    __shared__ float Bs[16][72];
    const int tid = threadIdx.x;
    const int bm = blockIdx.y * 64;
    const int bn = blockIdx.x * 64;
    const int tm = (tid / 16) * 4;
    const int tn = (tid % 16) * 4;
    const int lr = tid >> 2;
    const int lc = (tid & 3) * 4;
    float acc[4][4] = {{0.f}};
    for (int k0 = 0; k0 < K; k0 += 16) {
        float4 va = *(const float4*)&A[(size_t)(bm + lr) * K + k0 + lc];
        float4 vb = *(const float4*)&B[(size_t)(bn + lr) * K + k0 + lc];
        As[lc + 0][lr] = va.x; As[lc + 1][lr] = va.y;
        As[lc + 2][lr] = va.z; As[lc + 3][lr] = va.w;
        Bs[lc + 0][lr] = vb.x; Bs[lc + 1][lr] = vb.y;
        Bs[lc + 2][lr] = vb.z; Bs[lc + 3][lr] = vb.w;
        __syncthreads();
        #pragma unroll
        for (int kk = 0; kk < 16; ++kk) {
            float4 av = *(const float4*)&As[kk][tm];
            float4 bv = *(const float4*)&Bs[kk][tn];
            float ar[4] = {av.x, av.y, av.z, av.w};
            float br[4] = {bv.x, bv.y, bv.z, bv.w};
            #pragma unroll
            for (int i = 0; i < 4; ++i)
                #pragma unroll
                for (int j = 0; j < 4; ++j)
                    acc[i][j] = fmaf(ar[i], br[j], acc[i][j]);
        }
        __syncthreads();
    }
    float bsum[4];
    #pragma unroll
    for (int j = 0; j < 4; ++j) bsum[j] = bih[bn + tn + j] + bhh[bn + tn + j];
    #pragma unroll
    for (int i = 0; i < 4; ++i) {
        float4 o;
        o.x = acc[i][0] + bsum[0];
        o.y = acc[i][1] + bsum[1];
        o.z = acc[i][2] + bsum[2];
        o.w = acc[i][3] + bsum[3];
        *(float4*)&C[(size_t)(bm + tm + i) * N + bn + tn] = o;
    }
}

// xg row for d1 (decoder input is constant z): xgd1[r] = z . Wih[r,:] + bih[r] + bhh[r]
__global__ __launch_bounds__(512)
void xg_const_d1(const float* __restrict__ z, const float* __restrict__ Wih,
                 const float* __restrict__ bih, const float* __restrict__ bhh,
                 float* __restrict__ xgd1)
{
    __shared__ float zs[128];
    const int tid = threadIdx.x;
    if (tid < 128) zs[tid] = z[tid];
    __syncthreads();
    const float4* wr = (const float4*)(Wih + (size_t)tid * 128);
    float4 a4 = make_float4(0.f, 0.f, 0.f, 0.f);
    #pragma unroll
    for (int i = 0; i < 32; ++i) {
        float4 w = wr[i];
        float4 h = *(const float4*)&zs[i * 4];
        a4.x = fmaf(w.x, h.x, a4.x); a4.y = fmaf(w.y, h.y, a4.y);
        a4.z = fmaf(w.z, h.z, a4.z); a4.w = fmaf(w.w, h.w, a4.w);
    }
    xgd1[tid] = (a4.x + a4.y) + (a4.z + a4.w) + bih[tid] + bhh[tid];
}

// out[t] = ys[t][0:512] . Wo + bo   (one wave per t)
__global__ __launch_bounds__(256)
void out_gemv(const float* __restrict__ ys, const float* __restrict__ Wo,
              const float* __restrict__ bo, float* __restrict__ out)
{
    const int lane = threadIdx.x & 63;
    const int wid  = threadIdx.x >> 6;
    const int t = blockIdx.x * 4 + wid;
    const float* row = ys + (size_t)t * 512;
    float a = 0.f;
    #pragma unroll
    for (int i = 0; i < 8; ++i) a = fmaf(row[lane + i * 64], Wo[lane + i * 64], a);
    #pragma unroll
    for (int d = 1; d < 64; d <<= 1) a += __shfl_xor(a, d);
    if (lane == 0) out[t] = a + bo[0];
}

template<int H, int NWG, int TPB, int SUBS, int XGMODE, int LID, bool YS, bool Z>
static void launch_scan(const float* whh, const float* xg, const float* wih0,
                        const float* bih, const float* bhh, float* ys,
                        unsigned long long* hst, float* zout, hipStream_t stream)
{
    auto kfn = lstm_scan<H, NWG, TPB, SUBS, XGMODE, LID, YS, Z>;
    if (NWG > 1) {
        void* args[8] = {&whh, &xg, &wih0, &bih, &bhh, &ys, &hst, &zout};
        hipError_t e = hipLaunchCooperativeKernel(reinterpret_cast<void*>(kfn),
                                                  dim3(NWG), dim3(TPB), args, 0u, stream);
        if (e == hipSuccess) return;
        // fall back to a normal launch (<=32 small blocks co-reside on 256 CUs)
    }
    kfn<<<dim3(NWG), dim3(TPB), 0, stream>>>(whh, xg, wih0, bih, bhh, ys, hst, zout);
}

extern "C" void kernel_launch(void* const* d_in, const int* in_sizes, int n_in,
                              void* d_out, int out_size, void* d_ws, size_t ws_size,
                              hipStream_t stream)
{
    (void)in_sizes; (void)n_in; (void)out_size;
    const float* x = (const float*)d_in[0];
    const float* Wih[6]; const float* Whh[6]; const float* Bih[6]; const float* Bhh[6];
    for (int l = 0; l < 6; ++l) {
        Wih[l] = (const float*)d_in[1 + l * 4 + 0];
        Whh[l] = (const float*)d_in[1 + l * 4 + 1];
        Bih[l] = (const float*)d_in[1 + l * 4 + 2];
        Bhh[l] = (const float*)d_in[1 + l * 4 + 3];
    }
    const float* outW = (const float*)d_in[25];
    const float* outb = (const float*)d_in[26];

    // workspace layout (needs 128 MB + 4 KB)
    char* ws = (char*)d_ws;
    float* XG  = (float*)(ws);                                          // 64 MB max (d3)
    float* ysA = (float*)(ws + ((size_t)64 << 20));                     // 16 MB max
    float* ysB = (float*)(ws + ((size_t)80 << 20));                     // 16 MB max
    unsigned long long* HST = (unsigned long long*)(ws + ((size_t)96 << 20)); // 32 MB max
    float* z    = (float*)(ws + ((size_t)128 << 20));                   // 512 B
    float* xgd1 = (float*)(ws + ((size_t)128 << 20) + 1024);            // 2 KB
    if (ws_size < (((size_t)128 << 20) + 4096)) return;  // loudly fail absmax if ws too small

    // ---- encoder ----
    // e1: 1 -> 512, xg fused from scalar x[t]
    launch_scan<512, 32, 512, 8, 1, 1, true, false>(Whh[0], x, Wih[0], Bih[0], Bhh[0],
                                                    ysA, HST, nullptr, stream);
    // e2: 512 -> 256
    gemm_bias<<<dim3(1024 / 64, T_LEN / 64), 256, 0, stream>>>(ysA, Wih[1], Bih[1], Bhh[1],
                                                               XG, T_LEN, 1024, 512);
    launch_scan<256, 16, 512, 8, 0, 2, true, false>(Whh[1], XG, nullptr, nullptr, nullptr,
                                                    ysB, HST, nullptr, stream);
    // e3: 256 -> 128, only h_T needed
    gemm_bias<<<dim3(512 / 64, T_LEN / 64), 256, 0, stream>>>(ysB, Wih[2], Bih[2], Bhh[2],
                                                              XG, T_LEN, 512, 256);
    launch_scan<128, 1, 512, 1, 0, 0, false, true>(Whh[2], XG, nullptr, nullptr, nullptr,
                                                   nullptr, nullptr, z, stream);

    // ---- decoder ----
    // d1: constant input z, 128 -> 128
    xg_const_d1<<<1, 512, 0, stream>>>(z, Wih[3], Bih[3], Bhh[3], xgd1);
    launch_scan<128, 1, 512, 1, 2, 0, true, false>(Whh[3], xgd1, nullptr, nullptr, nullptr,
                                                   ysA, nullptr, nullptr, stream);
    // d2: 128 -> 256
    gemm_bias<<<dim3(1024 / 64, T_LEN / 64), 256, 0, stream>>>(ysA, Wih[4], Bih[4], Bhh[4],
                                                               XG, T_LEN, 1024, 128);
    launch_scan<256, 16, 512, 8, 0, 3, true, false>(Whh[4], XG, nullptr, nullptr, nullptr,
                                                    ysB, HST, nullptr, stream);
    // d3: 256 -> 512
    gemm_bias<<<dim3(2048 / 64, T_LEN / 64), 256, 0, stream>>>(ysB, Wih[5], Bih[5], Bhh[5],
                                                               XG, T_LEN, 2048, 256);
    launch_scan<512, 32, 512, 8, 0, 4, true, false>(Whh[5], XG, nullptr, nullptr, nullptr,
                                                    ysA, HST, nullptr, stream);

    // ---- output projection ----
    out_gemv<<<dim3(T_LEN / 4), 256, 0, stream>>>(ysA, outW, outb, (float*)d_out);
}